// Round 8
// baseline (338.723 us; speedup 1.0000x reference)
//
#include <hip/hip_runtime.h>

#define NN 12800
#define NE 204800

// ---------------- static device scratch (~14 MB) ----------------
__device__ __align__(16) float g_outA[NN * 16];  // node features ping
__device__ __align__(16) float g_outB[NN * 16];  // node features pong
__device__ __align__(16) float g_ehs[NE * 16];   // edge hidden, DST-sorted order
__device__ int g_src[NE];                        // src per dst-sorted edge
__device__ int g_dcnt[NN];                       // in-degree (CSR segment length)
__device__ int g_rowp[NN];                       // CSR row start (exclusive scan)
__device__ int g_cur[NN];                        // scatter cursor (copy of rowp)

// ---- S0: out0 = relu(x @ lin0_w.T + b); zero dcnt ----
__global__ __launch_bounds__(256) void k_setup(const float* __restrict__ x,
                                               const float* __restrict__ lw,
                                               const float* __restrict__ lb) {
    int n = blockIdx.x * 256 + threadIdx.x;
    float x0 = x[n * 3 + 0], x1 = x[n * 3 + 1], x2 = x[n * 3 + 2];
    float v[16];
#pragma unroll
    for (int j = 0; j < 16; ++j) {
        float t = lb[j] + x0 * lw[j * 3 + 0] + x1 * lw[j * 3 + 1] + x2 * lw[j * 3 + 2];
        v[j] = fmaxf(t, 0.0f);
    }
#pragma unroll
    for (int j = 0; j < 16; j += 4)
        *(float4*)(g_outA + n * 16 + j) = make_float4(v[j], v[j + 1], v[j + 2], v[j + 3]);
    g_dcnt[n] = 0;
}

// ---- S1: count dst occurrences ----
__global__ __launch_bounds__(256) void k_count(const int* __restrict__ ei) {
    int e = blockIdx.x * 256 + threadIdx.x;
    atomicAdd(&g_dcnt[ei[NE + e]], 1);
}

// ---- S2: exclusive scan dcnt -> rowp, cur ----
__global__ __launch_bounds__(256) void k_scan() {
    __shared__ int part[256];
    const int C = NN / 256;  // 50
    int t = threadIdx.x;
    int sum = 0;
    for (int i = 0; i < C; ++i) sum += g_dcnt[t * C + i];
    part[t] = sum;
    __syncthreads();
    for (int off = 1; off < 256; off <<= 1) {
        int v = (t >= off) ? part[t - off] : 0;
        __syncthreads();
        part[t] += v;
        __syncthreads();
    }
    int run = (t > 0) ? part[t - 1] : 0;
    for (int i = 0; i < C; ++i) {
        int idx = t * C + i;
        g_rowp[idx] = run;
        g_cur[idx] = run;
        run += g_dcnt[idx];
    }
}

// ---- S3: eh = relu(attr @ nn1_w.T + b1); scatter into dst-sorted slot ----
__global__ __launch_bounds__(256) void k_scatter(const int* __restrict__ ei,
                                                 const float* __restrict__ attr,
                                                 const float* __restrict__ w1,
                                                 const float* __restrict__ b1) {
    int e = blockIdx.x * 256 + threadIdx.x;
    int s = ei[e], d = ei[NE + e];
    float4 a = *(const float4*)(attr + e * 4);
    float v[16];
#pragma unroll
    for (int j = 0; j < 16; ++j) {
        float t = b1[j] + a.x * w1[j * 4 + 0] + a.y * w1[j * 4 + 1] +
                  a.z * w1[j * 4 + 2] + a.w * w1[j * 4 + 3];
        v[j] = fmaxf(t, 0.0f);
    }
    int pos = atomicAdd(&g_cur[d], 1);
    g_src[pos] = s;
#pragma unroll
    for (int j = 0; j < 16; j += 4)
        *(float4*)(g_ehs + pos * 16 + j) = make_float4(v[j], v[j + 1], v[j + 2], v[j + 3]);
}

// ---- one round, one dispatch, no atomics. 512 thr = 8 nodes x 1 wave. ----
// Wave per node. lane = t&63; q = lane>>4 (edge quarter), k = lane&15 (feature).
//   Quarter q accumulates G columns for edges q, q+4, ...  (4 independent
//   gather chains per wave). Quarters combined via shfl_xor 16/32.
//   Contraction: lane (q,k) computes T[i] for k' = 4q+i (sum over j at d=k),
//   then 4-stage xor butterfly over d; one publish shuffle routes a[k] back.
__global__ __launch_bounds__(512) void k_round(const float* __restrict__ nn2_w,
                                               const float* __restrict__ nn2_b,
                                               const float* __restrict__ cr,
                                               const float* __restrict__ cb,
                                               const float* __restrict__ wi,
                                               const float* __restrict__ wh,
                                               const float* __restrict__ bi,
                                               const float* __restrict__ bh,
                                               float* __restrict__ out_final,
                                               int flip, int last) {
    // s_W2[d*260 + k'*16 + j] = nn2_w[(d*16+k')*16 + j]  (stride 260: bank-spread)
    __shared__ float s_W2[16 * 260];
    __shared__ float s_b2[16 * 17];              // [d*17+k'] = nn2_b[d*16+k']
    __shared__ float s_cr[256], s_wiT[768], s_whT[768];
    __shared__ float s_cb[16], s_bi[48], s_bh[48];

    int t = threadIdx.x;
    for (int i = t; i < 4096; i += 512) {
        float v = nn2_w[i];
        int j = i & 15, mm = i >> 4, kp = mm & 15, d = mm >> 4;
        s_W2[d * 260 + kp * 16 + j] = v;
    }
    if (t < 256) {
        int d = t >> 4, kp = t & 15;
        s_b2[d * 17 + kp] = nn2_b[t];
        s_cr[t] = cr[t];                         // [d*16+k]
    }
    for (int i = t; i < 768; i += 512) {
        int row = i >> 4, d = i & 15;
        s_wiT[d * 48 + row] = wi[i];
        s_whT[d * 48 + row] = wh[i];
    }
    if (t < 16) s_cb[t] = cb[t];
    if (t < 48) { s_bi[t] = bi[t]; s_bh[t] = bh[t]; }
    __syncthreads();

    const float* cur = flip ? g_outB : g_outA;
    float*       nxt = flip ? g_outA : g_outB;

    const int lane = t & 63;
    const int q = lane >> 4, k = lane & 15;
    const int n = blockIdx.x * 8 + (t >> 6);     // one wave per node
    const int start = g_rowp[n];
    const int deg   = g_dcnt[n];

    // ---- G accumulation: quarter q takes edges qi = q, q+4, ... ----
    float Gk[17];
#pragma unroll
    for (int j = 0; j < 17; ++j) Gk[j] = 0.0f;
    int qi = q;
    int s0 = (qi < deg) ? g_src[start + qi] : 0;
#pragma unroll 2
    for (; qi < deg; qi += 4) {
        int p = start + qi;
        int s = s0;
        if (qi + 4 < deg) s0 = g_src[start + qi + 4];       // prefetch next src
        float ok = cur[s * 16 + k];              // 64B coalesced per quarter
        float4 e0 = *(const float4*)(g_ehs + p * 16 + 0);   // broadcast in quarter
        float4 e1 = *(const float4*)(g_ehs + p * 16 + 4);
        float4 e2 = *(const float4*)(g_ehs + p * 16 + 8);
        float4 e3 = *(const float4*)(g_ehs + p * 16 + 12);
        Gk[0]  += e0.x * ok; Gk[1]  += e0.y * ok; Gk[2]  += e0.z * ok; Gk[3]  += e0.w * ok;
        Gk[4]  += e1.x * ok; Gk[5]  += e1.y * ok; Gk[6]  += e1.z * ok; Gk[7]  += e1.w * ok;
        Gk[8]  += e2.x * ok; Gk[9]  += e2.y * ok; Gk[10] += e2.z * ok; Gk[11] += e2.w * ok;
        Gk[12] += e3.x * ok; Gk[13] += e3.y * ok; Gk[14] += e3.z * ok; Gk[15] += e3.w * ok;
        Gk[16] += ok;                            // bias row (eh == 1)
    }
    // combine quarters: all lanes end with full G column d=k
#pragma unroll
    for (int j = 0; j < 17; ++j) {
        Gk[j] += __shfl_xor(Gk[j], 16);
        Gk[j] += __shfl_xor(Gk[j], 32);
    }

    // ---- contraction: 4 outputs per lane (k' = 4q+i), butterfly over d ----
    float T[4];
    const float* wbase = s_W2 + k * 260;
#pragma unroll
    for (int i = 0; i < 4; ++i) {
        int kp = q * 4 + i;
        const float* w = wbase + kp * 16;
        float acc = Gk[16] * s_b2[k * 17 + kp];  // (sum_e 1) * bias term
#pragma unroll
        for (int jj = 0; jj < 4; ++jj) {
            int j = (((jj + q) & 3) << 2);       // j-phase rotated per quarter
            float4 wv = *(const float4*)(w + j);
            acc += Gk[j] * wv.x + Gk[j + 1] * wv.y + Gk[j + 2] * wv.z + Gk[j + 3] * wv.w;
        }
        T[i] = acc;
    }
#pragma unroll
    for (int msk = 1; msk <= 8; msk <<= 1) {
#pragma unroll
        for (int i = 0; i < 4; ++i) T[i] += __shfl_xor(T[i], msk);
    }
    // route: a[k] lives in quarter k>>2, slot k&3
    float pub   = T[k & 3];
    float a_sum = __shfl(pub, ((k >> 2) << 4) | (k & 3), 64);
    float invd  = 1.0f / (float)(deg > 0 ? deg : 1);
    float a_k   = a_sum * invd;

    // ---- node update (all quarters compute; quarter 0 stores) ----
    float o[16];
#pragma unroll
    for (int d = 0; d < 16; d += 4) {
        float4 v = *(const float4*)(cur + n * 16 + d);      // broadcast
        o[d] = v.x; o[d + 1] = v.y; o[d + 2] = v.z; o[d + 3] = v.w;
    }
    float mcc = s_cb[k] + a_k;
#pragma unroll
    for (int d = 0; d < 16; ++d) mcc += o[d] * s_cr[d * 16 + k];
    float m = fmaxf(mcc, 0.0f);

    float ir = s_bi[k], iz = s_bi[16 + k], in_ = s_bi[32 + k];
    float hr = s_bh[k], hz = s_bh[16 + k], hh = s_bh[32 + k];
#pragma unroll
    for (int d = 0; d < 16; ++d) {
        float md = __shfl(m, d, 16);
        ir  += md * s_wiT[d * 48 + k];
        iz  += md * s_wiT[d * 48 + 16 + k];
        in_ += md * s_wiT[d * 48 + 32 + k];
        hr  += o[d] * s_whT[d * 48 + k];
        hz  += o[d] * s_whT[d * 48 + 16 + k];
        hh  += o[d] * s_whT[d * 48 + 32 + k];
    }
    float rg = 1.0f / (1.0f + __expf(-(ir + hr)));
    float z  = 1.0f / (1.0f + __expf(-(iz + hz)));
    float nh = tanhf(in_ + rg * hh);
    float hnew = (1.0f - z) * nh + z * o[k];

    if (q == 0) {
        if (last) out_final[n * 16 + k] = hnew;
        else      nxt[n * 16 + k] = hnew;
    }
}

extern "C" void kernel_launch(void* const* d_in, const int* in_sizes, int n_in,
                              void* d_out, int out_size, void* d_ws, size_t ws_size,
                              hipStream_t stream) {
    const float* x         = (const float*)d_in[0];
    const int*   ei        = (const int*)d_in[1];
    const float* edge_attr = (const float*)d_in[2];
    const float* lin0_w    = (const float*)d_in[3];
    const float* lin0_b    = (const float*)d_in[4];
    const float* nn1_w     = (const float*)d_in[5];
    const float* nn1_b     = (const float*)d_in[6];
    const float* nn2_w     = (const float*)d_in[7];
    const float* nn2_b     = (const float*)d_in[8];
    const float* conv_root = (const float*)d_in[9];
    const float* conv_bias = (const float*)d_in[10];
    const float* gru_w_ih  = (const float*)d_in[11];
    const float* gru_w_hh  = (const float*)d_in[12];
    const float* gru_b_ih  = (const float*)d_in[13];
    const float* gru_b_hh  = (const float*)d_in[14];
    float* out = (float*)d_out;

    k_setup<<<NN / 256, 256, 0, stream>>>(x, lin0_w, lin0_b);
    k_count<<<NE / 256, 256, 0, stream>>>(ei);
    k_scan<<<1, 256, 0, stream>>>();
    k_scatter<<<NE / 256, 256, 0, stream>>>(ei, edge_attr, nn1_w, nn1_b);

    for (int r = 0; r < 6; ++r) {
        k_round<<<NN / 8, 512, 0, stream>>>(nn2_w, nn2_b, conv_root, conv_bias,
                                            gru_w_ih, gru_w_hh, gru_b_ih, gru_b_hh,
                                            out, r & 1, r == 5 ? 1 : 0);
    }
}